// Round 3
// baseline (1349.559 us; speedup 1.0000x reference)
//
#include <hip/hip_runtime.h>
#include <hip/hip_bf16.h>

// MSDeformAttn fused — R3: occupancy (VGPR<=128, LDS union), bf16 features,
// lane-linear packed A-fragments (conflict-free MFMA LDS reads).
// B=2, C=256, nH=8, nL=4, nP=4, hd=32, Len=21760.
// Shapes compile-time: [[128,128],[64,64],[32,32],[16,16]], starts [0,16384,20480,21504].

#define NH 8
#define NL 4
#define NP 4
#define CDIM 256
#define HD 32
#define QB 16

typedef short bf16x8 __attribute__((ext_vector_type(8)));
typedef short bf16x4 __attribute__((ext_vector_type(4)));
typedef float f32x4  __attribute__((ext_vector_type(4)));

__device__ __forceinline__ short f2bf(float x) {
    union { float f; unsigned u; } v; v.f = x;
    const unsigned r = v.u + 0x7FFFu + ((v.u >> 16) & 1u);
    return (short)(r >> 16);
}
__device__ __forceinline__ float bf2f(short s) {
    union { unsigned u; float f; } v; v.u = ((unsigned)(unsigned short)s) << 16;
    return v.f;
}

// ws layout: [0, 327680) bytes: Wt_off[256][256] | Wt_attn[128][256] | Wt_out[256][256] (bf16, [col][k])
//            [327680, ...) : feat_bf16 [B*Len*256] (bf16)
__global__ __launch_bounds__(256) void convert_w(
    const float* __restrict__ W_off, const float* __restrict__ W_attn,
    const float* __restrict__ W_out, short* __restrict__ wt)
{
    const int gid = blockIdx.x * 256 + threadIdx.x;
    if (gid < 65536) {
        const int c = gid >> 8, k = gid & 255;
        wt[gid] = f2bf(W_off[k * 256 + c]);
    } else if (gid < 98304) {
        const int g = gid - 65536, c = g >> 8, k = g & 255;
        wt[gid] = f2bf(W_attn[k * 128 + c]);
    } else if (gid < 163840) {
        const int g = gid - 98304, c = g >> 8, k = g & 255;
        wt[gid] = f2bf(W_out[k * 256 + c]);
    }
}

__global__ __launch_bounds__(256) void convert_feat(
    const float* __restrict__ feat, short* __restrict__ fb, int n4)
{
    const int gid = blockIdx.x * 256 + threadIdx.x;
    if (gid < n4) {
        const float4 v = *(const float4*)&feat[gid * 4];
        short4 o;
        o.x = f2bf(v.x); o.y = f2bf(v.y); o.z = f2bf(v.z); o.w = f2bf(v.w);
        *(short4*)&fb[gid * 4] = o;
    }
}

// FEATMODE: 1 = bf16 features from ws, 0 = fp32 features from input (ws too small)
template<int FEATMODE>
__global__ __launch_bounds__(256, 4) void msda_mfma(
    const float* __restrict__ query, const float* __restrict__ ref_pts,
    const float* __restrict__ feat_f32, const short* __restrict__ feat_bf,
    const short* __restrict__ wt,
    const float* __restrict__ b_off, const float* __restrict__ b_attn,
    const float* __restrict__ b_out, float* __restrict__ out, int Len)
{
    const int t = threadIdx.x;
    const int lane = t & 63;
    const int wave = t >> 6;
    const int qr = lane & 15;
    const int quad = lane >> 4;
    const long long qbase = (long long)blockIdx.x * QB;
    const int b = (int)(qbase / Len);

    // union: q packed (8 KB, phase 1) then offs [16][256] fp32 (16 KB, phases 2+)
    __shared__ __align__(16) char uni[QB * CDIM * 4];
    short* qp = (short*)uni;              // packed A-frags: chunk = s*64 + quad*16 + row
    float* offs_sm = (float*)uni;         // [i*256 + ((l*4+p)*2+xy)*8 + h]
    __shared__ float aw_sm[QB][NH * NL * NP + 4];  // [(l*4+p)*8 + h]
    __shared__ __align__(16) short pre_pack[QB * CDIM]; // packed A-frags for GEMM2
    __shared__ float ref_sm[QB][2];

    // ---- stage query (fp32 -> bf16, packed lane-linear) + ref ----
    #pragma unroll
    for (int it = 0; it < 4; ++it) {
        const int e = it * 1024 + t * 4;
        const int i = e >> 8, k = e & 255;
        const float4 v = *(const float4*)&query[(qbase + i) * CDIM + k];
        const int chunk = (k >> 5) * 64 + ((k >> 3) & 3) * 16 + i;
        short4 o;
        o.x = f2bf(v.x); o.y = f2bf(v.y); o.z = f2bf(v.z); o.w = f2bf(v.w);
        *(short4*)&qp[chunk * 8 + (k & 7)] = o;
    }
    if (t < QB * 2) ref_sm[t >> 1][t & 1] = ref_pts[(qbase + (t >> 1)) * 2 + (t & 1)];
    __syncthreads();

    const short* __restrict__ Wt_off  = wt;
    const short* __restrict__ Wt_attn = wt + 65536;
    const short* __restrict__ Wt_out  = wt + 98304;

    // ---- GEMM1 (offsets N=256) + GEMM-attn (N=128) ----
    {
        f32x4 acc[4], acca[2];
        #pragma unroll
        for (int j = 0; j < 4; ++j) acc[j] = (f32x4){0.f, 0.f, 0.f, 0.f};
        #pragma unroll
        for (int j = 0; j < 2; ++j) acca[j] = (f32x4){0.f, 0.f, 0.f, 0.f};

        const short* bb_off  = Wt_off  + qr * 256 + quad * 8;
        const short* bb_attn = Wt_attn + qr * 256 + quad * 8;
        #pragma unroll
        for (int s = 0; s < 8; ++s) {
            const bf16x8 af = *(const bf16x8*)&qp[(s * 64 + lane) * 8];
            #pragma unroll
            for (int j = 0; j < 4; ++j) {
                const bf16x8 bf = *(const bf16x8*)(bb_off + ((j * 4 + wave) * 16) * 256 + s * 32);
                acc[j] = __builtin_amdgcn_mfma_f32_16x16x32_bf16(af, bf, acc[j], 0, 0, 0);
            }
            #pragma unroll
            for (int j = 0; j < 2; ++j) {
                const bf16x8 bf = *(const bf16x8*)(bb_attn + ((j * 4 + wave) * 16) * 256 + s * 32);
                acca[j] = __builtin_amdgcn_mfma_f32_16x16x32_bf16(af, bf, acca[j], 0, 0, 0);
            }
        }
        __syncthreads();   // q reads done everywhere; union becomes offs_sm

        // C/D: col = lane&15 (here qr), row = quad*4 + r
        #pragma unroll
        for (int j = 0; j < 4; ++j) {
            const int col = (j * 4 + wave) * 16 + qr;
            const float bo = b_off[col];
            const int h = col >> 5, rem = col & 31;
            const int colp = rem * 8 + h;
            #pragma unroll
            for (int r = 0; r < 4; ++r)
                offs_sm[(quad * 4 + r) * 256 + colp] = acc[j][r] + bo;
        }
        #pragma unroll
        for (int j = 0; j < 2; ++j) {
            const int col = (j * 4 + wave) * 16 + qr;
            const float ba = b_attn[col];
            const int h = col >> 4, rem = col & 15;
            const int colp = rem * 8 + h;
            #pragma unroll
            for (int r = 0; r < 4; ++r)
                aw_sm[quad * 4 + r][colp] = acca[j][r] + ba;
        }
    }
    __syncthreads();

    // ---- softmax per (row, head) over 16 points ----
    if (t < QB * NH) {
        const int i = t >> 3, h = t & 7;
        float vals[16], mx = -1e30f;
        #pragma unroll
        for (int j = 0; j < 16; ++j) { vals[j] = aw_sm[i][j * 8 + h]; mx = fmaxf(mx, vals[j]); }
        float s = 0.f;
        #pragma unroll
        for (int j = 0; j < 16; ++j) { vals[j] = __expf(vals[j] - mx); s += vals[j]; }
        const float inv = 1.f / s;
        #pragma unroll
        for (int j = 0; j < 16; ++j) aw_sm[i][j * 8 + h] = vals[j] * inv;
    }
    __syncthreads();

    // ---- sampling: lane = q2*32 + h*4 + ct; 8 bf16 channels per thread ----
    {
        const int q2 = lane >> 5;
        const int h = (lane >> 2) & 7;
        const int ct = lane & 3;
        const int c0 = h * HD + ct * 8;
        const int LVL_W[4] = {128, 64, 32, 16};
        const int LVL_S[4] = {0, 16384, 20480, 21504};
        #pragma unroll
        for (int it = 0; it < 2; ++it) {
            const int i = wave * 4 + it * 2 + q2;
            const float rx = ref_sm[i][0], ry = ref_sm[i][1];
            float acc[8];
            #pragma unroll
            for (int c = 0; c < 8; ++c) acc[c] = 0.f;
            #pragma unroll
            for (int l = 0; l < NL; ++l) {
                const int Wl = LVL_W[l];
                const long long lbase = (long long)(b * Len + LVL_S[l]) * CDIM + c0;
                #pragma unroll
                for (int p = 0; p < NP; ++p) {
                    const int pi = l * 4 + p;
                    const float ox = offs_sm[i * 256 + (pi * 2) * 8 + h];
                    const float oy = offs_sm[i * 256 + (pi * 2 + 1) * 8 + h];
                    const float a  = aw_sm[i][pi * 8 + h];
                    const float x = fmaf(rx, (float)Wl, ox) - 0.5f;
                    const float y = fmaf(ry, (float)Wl, oy) - 0.5f;
                    const float xf = floorf(x), yf = floorf(y);
                    const int x0 = (int)xf, y0 = (int)yf;
                    const float wx = x - xf, wy = y - yf;
                    const bool xok0 = (x0 >= 0) & (x0 < Wl);
                    const bool xok1 = (x0 + 1 >= 0) & (x0 + 1 < Wl);
                    const bool yok0 = (y0 >= 0) & (y0 < Wl);
                    const bool yok1 = (y0 + 1 >= 0) & (y0 + 1 < Wl);
                    const float w00 = (1.f - wx) * (1.f - wy) * a;
                    const float w01 = wx * (1.f - wy) * a;
                    const float w10 = (1.f - wx) * wy * a;
                    const float w11 = wx * wy * a;
                    const long long r0 = lbase + (long long)(y0 * Wl + x0) * CDIM;
                    if (FEATMODE == 1) {
                        bf16x8 v00 = {0,0,0,0,0,0,0,0}, v01 = v00, v10 = v00, v11 = v00;
                        if (yok0 & xok0) v00 = *(const bf16x8*)(feat_bf + r0);
                        if (yok0 & xok1) v01 = *(const bf16x8*)(feat_bf + r0 + CDIM);
                        if (yok1 & xok0) v10 = *(const bf16x8*)(feat_bf + r0 + Wl * CDIM);
                        if (yok1 & xok1) v11 = *(const bf16x8*)(feat_bf + r0 + (Wl + 1) * CDIM);
                        #pragma unroll
                        for (int c = 0; c < 8; ++c) {
                            float s = w00 * bf2f(v00[c]);
                            s = fmaf(w01, bf2f(v01[c]), s);
                            s = fmaf(w10, bf2f(v10[c]), s);
                            s = fmaf(w11, bf2f(v11[c]), s);
                            acc[c] += s;
                        }
                    } else {
                        f32x4 a0 = (f32x4){0.f,0.f,0.f,0.f}, a1 = a0, b0 = a0, b1 = a0;
                        f32x4 c0v = a0, c1 = a0, d0 = a0, d1 = a0;
                        if (yok0 & xok0) { a0 = *(const f32x4*)(feat_f32 + r0);
                                           a1 = *(const f32x4*)(feat_f32 + r0 + 4); }
                        if (yok0 & xok1) { b0 = *(const f32x4*)(feat_f32 + r0 + CDIM);
                                           b1 = *(const f32x4*)(feat_f32 + r0 + CDIM + 4); }
                        if (yok1 & xok0) { c0v = *(const f32x4*)(feat_f32 + r0 + Wl * CDIM);
                                           c1 = *(const f32x4*)(feat_f32 + r0 + Wl * CDIM + 4); }
                        if (yok1 & xok1) { d0 = *(const f32x4*)(feat_f32 + r0 + (Wl + 1) * CDIM);
                                           d1 = *(const f32x4*)(feat_f32 + r0 + (Wl + 1) * CDIM + 4); }
                        #pragma unroll
                        for (int c = 0; c < 4; ++c) {
                            acc[c]     += w00*a0[c] + w01*b0[c] + w10*c0v[c] + w11*d0[c];
                            acc[c + 4] += w00*a1[c] + w01*b1[c] + w10*c1[c]  + w11*d1[c];
                        }
                    }
                }
            }
            bf16x8 pv;
            #pragma unroll
            for (int c = 0; c < 8; ++c) pv[c] = f2bf(acc[c]);
            const int chunk = h * 64 + ct * 16 + i;   // (s=h, quad=ct, row=i)
            *(bf16x8*)&pre_pack[chunk * 8] = pv;
        }
    }
    __syncthreads();

    // ---- GEMM2: out = pre @ W_out + b_out ----
    {
        f32x4 acc[4];
        #pragma unroll
        for (int j = 0; j < 4; ++j) acc[j] = (f32x4){0.f, 0.f, 0.f, 0.f};
        const short* bb = Wt_out + qr * 256 + quad * 8;
        #pragma unroll
        for (int s = 0; s < 8; ++s) {
            const bf16x8 af = *(const bf16x8*)&pre_pack[(s * 64 + lane) * 8];
            #pragma unroll
            for (int j = 0; j < 4; ++j) {
                const bf16x8 bf = *(const bf16x8*)(bb + ((j * 4 + wave) * 16) * 256 + s * 32);
                acc[j] = __builtin_amdgcn_mfma_f32_16x16x32_bf16(af, bf, acc[j], 0, 0, 0);
            }
        }
        #pragma unroll
        for (int j = 0; j < 4; ++j) {
            const int col = (j * 4 + wave) * 16 + qr;
            const float bo = b_out[col];
            #pragma unroll
            for (int r = 0; r < 4; ++r)
                out[(qbase + quad * 4 + r) * CDIM + col] = acc[j][r] + bo;
        }
    }
}

extern "C" void kernel_launch(void* const* d_in, const int* in_sizes, int n_in,
                              void* d_out, int out_size, void* d_ws, size_t ws_size,
                              hipStream_t stream) {
    const float* query   = (const float*)d_in[0];
    const float* ref_pts = (const float*)d_in[1];
    const float* feat    = (const float*)d_in[2];
    const float* W_off  = (const float*)d_in[5];
    const float* b_off  = (const float*)d_in[6];
    const float* W_attn = (const float*)d_in[7];
    const float* b_attn = (const float*)d_in[8];
    const float* W_out  = (const float*)d_in[9];
    const float* b_out  = (const float*)d_in[10];
    float* out = (float*)d_out;
    short* wt = (short*)d_ws;

    const int B = 2;
    const int Len = in_sizes[1] / (B * 2);
    const int rows = B * Len;
    const int grid = rows / QB;
    const size_t feat_elems = (size_t)B * Len * CDIM;
    const size_t need = 327680 + feat_elems * 2;

    convert_w<<<640, 256, 0, stream>>>(W_off, W_attn, W_out, wt);

    if (ws_size >= need) {
        short* featbf = wt + 163840;
        const int n4 = (int)(feat_elems / 4);
        convert_feat<<<(n4 + 255) / 256, 256, 0, stream>>>(feat, featbf, n4);
        msda_mfma<1><<<grid, 256, 0, stream>>>(query, ref_pts, feat, featbf, wt,
                                               b_off, b_attn, b_out, out, Len);
    } else {
        msda_mfma<0><<<grid, 256, 0, stream>>>(query, ref_pts, feat, (const short*)nullptr, wt,
                                               b_off, b_attn, b_out, out, Len);
    }
}

// Round 4
// 415.776 us; speedup vs baseline: 3.2459x; 3.2459x over previous
//
#include <hip/hip_runtime.h>

// MSDeformAttn — R4: split pipeline.
//   convert_w / convert_feat -> gemm1 (MFMA, offs+attn) -> sampler (lean, no LDS)
//   -> gemm2 (MFMA, no LDS). Fallback: fused kernel (no register cap) if ws small.
// B=2, C=256, nH=8, nL=4, nP=4, hd=32, Len=21760.
// Shapes compile-time: [[128,128],[64,64],[32,32],[16,16]], starts [0,16384,20480,21504].

#define NH 8
#define NL 4
#define NP 4
#define CDIM 256
#define HD 32
#define QB 16

typedef short bf16x8 __attribute__((ext_vector_type(8)));
typedef float f32x4  __attribute__((ext_vector_type(4)));

__device__ __forceinline__ short f2bf(float x) {
    union { float f; unsigned u; } v; v.f = x;
    const unsigned r = v.u + 0x7FFFu + ((v.u >> 16) & 1u);
    return (short)(r >> 16);
}
__device__ __forceinline__ float bf2f(short s) {
    union { unsigned u; float f; } v; v.u = ((unsigned)(unsigned short)s) << 16;
    return v.f;
}

__constant__ int LVL_S_C[4] = {0, 16384, 20480, 21504};

// ---- converts ----
__global__ __launch_bounds__(256) void convert_w(
    const float* __restrict__ W_off, const float* __restrict__ W_attn,
    const float* __restrict__ W_out, short* __restrict__ wt)
{
    const int gid = blockIdx.x * 256 + threadIdx.x;
    if (gid < 65536) {
        const int c = gid >> 8, k = gid & 255;
        wt[gid] = f2bf(W_off[k * 256 + c]);
    } else if (gid < 98304) {
        const int g = gid - 65536, c = g >> 8, k = g & 255;
        wt[gid] = f2bf(W_attn[k * 128 + c]);
    } else if (gid < 163840) {
        const int g = gid - 98304, c = g >> 8, k = g & 255;
        wt[gid] = f2bf(W_out[k * 256 + c]);
    }
}

__global__ __launch_bounds__(256) void convert_feat(
    const float* __restrict__ feat, short* __restrict__ fb, int n4)
{
    const int gid = blockIdx.x * 256 + threadIdx.x;
    if (gid < n4) {
        const float4 v = *(const float4*)&feat[gid * 4];
        short4 o;
        o.x = f2bf(v.x); o.y = f2bf(v.y); o.z = f2bf(v.z); o.w = f2bf(v.w);
        *(short4*)&fb[gid * 4] = o;
    }
}

// ---- gemm1: offs (N=256) + attn logits (N=128), 16 rows/block ----
__global__ __launch_bounds__(256) void gemm1_kernel(
    const float* __restrict__ query, const short* __restrict__ wt,
    const float* __restrict__ b_off, const float* __restrict__ b_attn,
    float* __restrict__ offs_g, float* __restrict__ aw_g)
{
    const int t = threadIdx.x;
    const int lane = t & 63;
    const int wave = t >> 6;
    const int qr = lane & 15;
    const int quad = lane >> 4;
    const long long qbase = (long long)blockIdx.x * QB;

    __shared__ __align__(16) short qp[QB * CDIM];  // packed A-frags

    #pragma unroll
    for (int it = 0; it < 4; ++it) {
        const int e = it * 1024 + t * 4;
        const int i = e >> 8, k = e & 255;
        const float4 v = *(const float4*)&query[(qbase + i) * CDIM + k];
        const int chunk = (k >> 5) * 64 + ((k >> 3) & 3) * 16 + i;
        short4 o;
        o.x = f2bf(v.x); o.y = f2bf(v.y); o.z = f2bf(v.z); o.w = f2bf(v.w);
        *(short4*)&qp[chunk * 8 + (k & 7)] = o;
    }
    __syncthreads();

    const short* __restrict__ Wt_off  = wt;
    const short* __restrict__ Wt_attn = wt + 65536;

    f32x4 acc[4], acca[2];
    #pragma unroll
    for (int j = 0; j < 4; ++j) acc[j] = (f32x4){0.f, 0.f, 0.f, 0.f};
    #pragma unroll
    for (int j = 0; j < 2; ++j) acca[j] = (f32x4){0.f, 0.f, 0.f, 0.f};

    const short* bb_off  = Wt_off  + qr * 256 + quad * 8;
    const short* bb_attn = Wt_attn + qr * 256 + quad * 8;
    #pragma unroll
    for (int s = 0; s < 8; ++s) {
        const bf16x8 af = *(const bf16x8*)&qp[(s * 64 + lane) * 8];
        #pragma unroll
        for (int j = 0; j < 4; ++j) {
            const bf16x8 bf = *(const bf16x8*)(bb_off + ((j * 4 + wave) * 16) * 256 + s * 32);
            acc[j] = __builtin_amdgcn_mfma_f32_16x16x32_bf16(af, bf, acc[j], 0, 0, 0);
        }
        #pragma unroll
        for (int j = 0; j < 2; ++j) {
            const bf16x8 bf = *(const bf16x8*)(bb_attn + ((j * 4 + wave) * 16) * 256 + s * 32);
            acca[j] = __builtin_amdgcn_mfma_f32_16x16x32_bf16(af, bf, acca[j], 0, 0, 0);
        }
    }
    // D layout: col = qr (n), row = quad*4 + r (m). Permuted stores for sampler.
    #pragma unroll
    for (int j = 0; j < 4; ++j) {
        const int col = (j * 4 + wave) * 16 + qr;
        const float bo = b_off[col];
        const int h = col >> 5, rem = col & 31;
        const int colp = rem * 8 + h;
        #pragma unroll
        for (int r = 0; r < 4; ++r)
            offs_g[(qbase + quad * 4 + r) * 256 + colp] = acc[j][r] + bo;
    }
    #pragma unroll
    for (int j = 0; j < 2; ++j) {
        const int col = (j * 4 + wave) * 16 + qr;
        const float ba = b_attn[col];
        const int h = col >> 4, rem = col & 15;
        const int colp = rem * 8 + h;
        #pragma unroll
        for (int r = 0; r < 4; ++r)
            aw_g[(qbase + quad * 4 + r) * 128 + colp] = acca[j][r] + ba;
    }
}

// ---- sampler: 8 rows/block, 32 lanes/row (h = l32>>2, ct = l32&3, 8 ch each) ----
__global__ __launch_bounds__(256) void sampler_kernel(
    const float* __restrict__ ref_pts, const short* __restrict__ featbf,
    const float* __restrict__ offs_g, const float* __restrict__ aw_g,
    short* __restrict__ pre_g, int Len)
{
    const int t = threadIdx.x;
    const int rl = t >> 5;
    const int l32 = t & 31;
    const int h = l32 >> 2, ct = l32 & 3;
    const int row = blockIdx.x * 8 + rl;
    const int b = row / Len;

    const float rx = ref_pts[row * 2];
    const float ry = ref_pts[row * 2 + 1];
    const float* __restrict__ offr = offs_g + (long long)row * 256;
    const float* __restrict__ awr  = aw_g  + (long long)row * 128;

    // softmax stats over 16 logits for this (row, h) — streamed, only mx/inv live
    float mx = -1e30f;
    #pragma unroll
    for (int j = 0; j < 16; ++j) mx = fmaxf(mx, awr[j * 8 + h]);
    float ssum = 0.f;
    #pragma unroll
    for (int j = 0; j < 16; ++j) ssum += __expf(awr[j * 8 + h] - mx);
    const float inv = 1.f / ssum;

    const int c0 = h * HD + ct * 8;
    float acc[8];
    #pragma unroll
    for (int c = 0; c < 8; ++c) acc[c] = 0.f;

    #pragma unroll
    for (int l = 0; l < NL; ++l) {
        const int Wl = 128 >> l;
        const int base = (b * Len + LVL_S_C[l]) * CDIM + c0;
        #pragma unroll 2
        for (int p = 0; p < NP; ++p) {
            const int pi = l * 4 + p;
            const float ox = offr[(pi * 2) * 8 + h];
            const float oy = offr[(pi * 2 + 1) * 8 + h];
            const float a  = __expf(awr[pi * 8 + h] - mx) * inv;
            const float x = fmaf(rx, (float)Wl, ox) - 0.5f;
            const float y = fmaf(ry, (float)Wl, oy) - 0.5f;
            const float xf = floorf(x), yf = floorf(y);
            const int x0 = (int)xf, y0 = (int)yf;
            const float wx = x - xf, wy = y - yf;
            const bool xok0 = (x0 >= 0) & (x0 < Wl);
            const bool xok1 = (x0 + 1 >= 0) & (x0 + 1 < Wl);
            const bool yok0 = (y0 >= 0) & (y0 < Wl);
            const bool yok1 = (y0 + 1 >= 0) & (y0 + 1 < Wl);
            const float w00 = (1.f - wx) * (1.f - wy) * a;
            const float w01 = wx * (1.f - wy) * a;
            const float w10 = (1.f - wx) * wy * a;
            const float w11 = wx * wy * a;
            const int r0 = base + (y0 * Wl + x0) * CDIM;
            bf16x8 v00 = {0,0,0,0,0,0,0,0}, v01 = v00, v10 = v00, v11 = v00;
            if (yok0 & xok0) v00 = *(const bf16x8*)(featbf + r0);
            if (yok0 & xok1) v01 = *(const bf16x8*)(featbf + r0 + CDIM);
            if (yok1 & xok0) v10 = *(const bf16x8*)(featbf + r0 + Wl * CDIM);
            if (yok1 & xok1) v11 = *(const bf16x8*)(featbf + r0 + (Wl + 1) * CDIM);
            #pragma unroll
            for (int c = 0; c < 8; ++c) {
                float s = w00 * bf2f(v00[c]);
                s = fmaf(w01, bf2f(v01[c]), s);
                s = fmaf(w10, bf2f(v10[c]), s);
                s = fmaf(w11, bf2f(v11[c]), s);
                acc[c] += s;
            }
        }
    }
    bf16x8 pv;
    #pragma unroll
    for (int c = 0; c < 8; ++c) pv[c] = f2bf(acc[c]);
    // packed A-frag layout for gemm2: chunk = h*64 + ct*16 + (row&15), tile = row>>4
    *(bf16x8*)&pre_g[(long long)(row >> 4) * 4096 + (h * 64 + ct * 16 + (row & 15)) * 8] = pv;
}

// ---- gemm2: out = pre @ W_out + b_out, 16 rows/block, no LDS ----
__global__ __launch_bounds__(256) void gemm2_kernel(
    const short* __restrict__ pre_g, const short* __restrict__ wt,
    const float* __restrict__ b_out, float* __restrict__ out)
{
    const int t = threadIdx.x;
    const int lane = t & 63;
    const int wave = t >> 6;
    const int qr = lane & 15;
    const int quad = lane >> 4;
    const long long qbase = (long long)blockIdx.x * QB;
    const short* __restrict__ ap = pre_g + (long long)blockIdx.x * 4096;
    const short* __restrict__ Wt_out = wt + 98304;

    f32x4 acc[4];
    #pragma unroll
    for (int j = 0; j < 4; ++j) acc[j] = (f32x4){0.f, 0.f, 0.f, 0.f};
    const short* bb = Wt_out + qr * 256 + quad * 8;
    #pragma unroll
    for (int s = 0; s < 8; ++s) {
        const bf16x8 af = *(const bf16x8*)&ap[(s * 64 + lane) * 8];
        #pragma unroll
        for (int j = 0; j < 4; ++j) {
            const bf16x8 bf = *(const bf16x8*)(bb + ((j * 4 + wave) * 16) * 256 + s * 32);
            acc[j] = __builtin_amdgcn_mfma_f32_16x16x32_bf16(af, bf, acc[j], 0, 0, 0);
        }
    }
    #pragma unroll
    for (int j = 0; j < 4; ++j) {
        const int col = (j * 4 + wave) * 16 + qr;
        const float bo = b_out[col];
        #pragma unroll
        for (int r = 0; r < 4; ++r)
            out[(qbase + quad * 4 + r) * CDIM + col] = acc[j][r] + bo;
    }
}

// ---- fallback fused kernel (ws too small for split) ----
template<int FEATMODE>
__global__ __launch_bounds__(256) void msda_fused_fb(
    const float* __restrict__ query, const float* __restrict__ ref_pts,
    const float* __restrict__ feat_f32, const short* __restrict__ feat_bf,
    const short* __restrict__ wt,
    const float* __restrict__ b_off, const float* __restrict__ b_attn,
    const float* __restrict__ b_out, float* __restrict__ out, int Len)
{
    const int t = threadIdx.x;
    const int lane = t & 63;
    const int wave = t >> 6;
    const int qr = lane & 15;
    const int quad = lane >> 4;
    const long long qbase = (long long)blockIdx.x * QB;
    const int b = (int)(qbase / Len);

    __shared__ __align__(16) char uni[QB * CDIM * 4];
    short* qp = (short*)uni;
    float* offs_sm = (float*)uni;
    __shared__ float aw_sm[QB][NH * NL * NP + 4];
    __shared__ __align__(16) short pre_pack[QB * CDIM];
    __shared__ float ref_sm[QB][2];

    #pragma unroll
    for (int it = 0; it < 4; ++it) {
        const int e = it * 1024 + t * 4;
        const int i = e >> 8, k = e & 255;
        const float4 v = *(const float4*)&query[(qbase + i) * CDIM + k];
        const int chunk = (k >> 5) * 64 + ((k >> 3) & 3) * 16 + i;
        short4 o;
        o.x = f2bf(v.x); o.y = f2bf(v.y); o.z = f2bf(v.z); o.w = f2bf(v.w);
        *(short4*)&qp[chunk * 8 + (k & 7)] = o;
    }
    if (t < QB * 2) ref_sm[t >> 1][t & 1] = ref_pts[(qbase + (t >> 1)) * 2 + (t & 1)];
    __syncthreads();

    const short* __restrict__ Wt_off  = wt;
    const short* __restrict__ Wt_attn = wt + 65536;
    const short* __restrict__ Wt_out  = wt + 98304;

    {
        f32x4 acc[4], acca[2];
        #pragma unroll
        for (int j = 0; j < 4; ++j) acc[j] = (f32x4){0.f, 0.f, 0.f, 0.f};
        #pragma unroll
        for (int j = 0; j < 2; ++j) acca[j] = (f32x4){0.f, 0.f, 0.f, 0.f};
        const short* bb_off  = Wt_off  + qr * 256 + quad * 8;
        const short* bb_attn = Wt_attn + qr * 256 + quad * 8;
        #pragma unroll
        for (int s = 0; s < 8; ++s) {
            const bf16x8 af = *(const bf16x8*)&qp[(s * 64 + lane) * 8];
            #pragma unroll
            for (int j = 0; j < 4; ++j) {
                const bf16x8 bf = *(const bf16x8*)(bb_off + ((j * 4 + wave) * 16) * 256 + s * 32);
                acc[j] = __builtin_amdgcn_mfma_f32_16x16x32_bf16(af, bf, acc[j], 0, 0, 0);
            }
            #pragma unroll
            for (int j = 0; j < 2; ++j) {
                const bf16x8 bf = *(const bf16x8*)(bb_attn + ((j * 4 + wave) * 16) * 256 + s * 32);
                acca[j] = __builtin_amdgcn_mfma_f32_16x16x32_bf16(af, bf, acca[j], 0, 0, 0);
            }
        }
        __syncthreads();
        #pragma unroll
        for (int j = 0; j < 4; ++j) {
            const int col = (j * 4 + wave) * 16 + qr;
            const float bo = b_off[col];
            const int h = col >> 5, rem = col & 31;
            #pragma unroll
            for (int r = 0; r < 4; ++r)
                offs_sm[(quad * 4 + r) * 256 + rem * 8 + h] = acc[j][r] + bo;
        }
        #pragma unroll
        for (int j = 0; j < 2; ++j) {
            const int col = (j * 4 + wave) * 16 + qr;
            const float ba = b_attn[col];
            const int h = col >> 4, rem = col & 15;
            #pragma unroll
            for (int r = 0; r < 4; ++r)
                aw_sm[quad * 4 + r][rem * 8 + h] = acca[j][r] + ba;
        }
    }
    __syncthreads();

    if (t < QB * NH) {
        const int i = t >> 3, h = t & 7;
        float vals[16], mx = -1e30f;
        #pragma unroll
        for (int j = 0; j < 16; ++j) { vals[j] = aw_sm[i][j * 8 + h]; mx = fmaxf(mx, vals[j]); }
        float s = 0.f;
        #pragma unroll
        for (int j = 0; j < 16; ++j) { vals[j] = __expf(vals[j] - mx); s += vals[j]; }
        const float inv = 1.f / s;
        #pragma unroll
        for (int j = 0; j < 16; ++j) aw_sm[i][j * 8 + h] = vals[j] * inv;
    }
    __syncthreads();

    {
        const int q2 = lane >> 5;
        const int h = (lane >> 2) & 7;
        const int ct = lane & 3;
        const int c0 = h * HD + ct * 8;
        #pragma unroll 1
        for (int it = 0; it < 2; ++it) {
            const int i = wave * 4 + it * 2 + q2;
            const float rx = ref_sm[i][0], ry = ref_sm[i][1];
            float acc[8];
            #pragma unroll
            for (int c = 0; c < 8; ++c) acc[c] = 0.f;
            #pragma unroll
            for (int l = 0; l < NL; ++l) {
                const int Wl = 128 >> l;
                const int base = (b * Len + LVL_S_C[l]) * CDIM + c0;
                #pragma unroll 2
                for (int p = 0; p < NP; ++p) {
                    const int pi = l * 4 + p;
                    const float ox = offs_sm[i * 256 + (pi * 2) * 8 + h];
                    const float oy = offs_sm[i * 256 + (pi * 2 + 1) * 8 + h];
                    const float a  = aw_sm[i][pi * 8 + h];
                    const float x = fmaf(rx, (float)Wl, ox) - 0.5f;
                    const float y = fmaf(ry, (float)Wl, oy) - 0.5f;
                    const float xf = floorf(x), yf = floorf(y);
                    const int x0 = (int)xf, y0 = (int)yf;
                    const float wx = x - xf, wy = y - yf;
                    const bool xok0 = (x0 >= 0) & (x0 < Wl);
                    const bool xok1 = (x0 + 1 >= 0) & (x0 + 1 < Wl);
                    const bool yok0 = (y0 >= 0) & (y0 < Wl);
                    const bool yok1 = (y0 + 1 >= 0) & (y0 + 1 < Wl);
                    const float w00 = (1.f - wx) * (1.f - wy) * a;
                    const float w01 = wx * (1.f - wy) * a;
                    const float w10 = (1.f - wx) * wy * a;
                    const float w11 = wx * wy * a;
                    const int r0 = base + (y0 * Wl + x0) * CDIM;
                    if (FEATMODE == 1) {
                        bf16x8 v00 = {0,0,0,0,0,0,0,0}, v01 = v00, v10 = v00, v11 = v00;
                        if (yok0 & xok0) v00 = *(const bf16x8*)(feat_bf + r0);
                        if (yok0 & xok1) v01 = *(const bf16x8*)(feat_bf + r0 + CDIM);
                        if (yok1 & xok0) v10 = *(const bf16x8*)(feat_bf + r0 + Wl * CDIM);
                        if (yok1 & xok1) v11 = *(const bf16x8*)(feat_bf + r0 + (Wl + 1) * CDIM);
                        #pragma unroll
                        for (int c = 0; c < 8; ++c) {
                            float s = w00 * bf2f(v00[c]);
                            s = fmaf(w01, bf2f(v01[c]), s);
                            s = fmaf(w10, bf2f(v10[c]), s);
                            s = fmaf(w11, bf2f(v11[c]), s);
                            acc[c] += s;
                        }
                    } else {
                        f32x4 a0 = (f32x4){0.f,0.f,0.f,0.f}, a1 = a0, b0 = a0, b1 = a0;
                        f32x4 c0v = a0, c1 = a0, d0 = a0, d1 = a0;
                        if (yok0 & xok0) { a0 = *(const f32x4*)(feat_f32 + r0);
                                           a1 = *(const f32x4*)(feat_f32 + r0 + 4); }
                        if (yok0 & xok1) { b0 = *(const f32x4*)(feat_f32 + r0 + CDIM);
                                           b1 = *(const f32x4*)(feat_f32 + r0 + CDIM + 4); }
                        if (yok1 & xok0) { c0v = *(const f32x4*)(feat_f32 + r0 + Wl * CDIM);
                                           c1 = *(const f32x4*)(feat_f32 + r0 + Wl * CDIM + 4); }
                        if (yok1 & xok1) { d0 = *(const f32x4*)(feat_f32 + r0 + (Wl + 1) * CDIM);
                                           d1 = *(const f32x4*)(feat_f32 + r0 + (Wl + 1) * CDIM + 4); }
                        #pragma unroll
                        for (int c = 0; c < 4; ++c) {
                            acc[c]     += w00*a0[c] + w01*b0[c] + w10*c0v[c] + w11*d0[c];
                            acc[c + 4] += w00*a1[c] + w01*b1[c] + w10*c1[c]  + w11*d1[c];
                        }
                    }
                }
            }
            bf16x8 pv;
            #pragma unroll
            for (int c = 0; c < 8; ++c) pv[c] = f2bf(acc[c]);
            *(bf16x8*)&pre_pack[(h * 64 + ct * 16 + i) * 8] = pv;
        }
    }
    __syncthreads();

    {
        f32x4 acc[4];
        #pragma unroll
        for (int j = 0; j < 4; ++j) acc[j] = (f32x4){0.f, 0.f, 0.f, 0.f};
        const short* bb = Wt_out + qr * 256 + quad * 8;
        #pragma unroll
        for (int s = 0; s < 8; ++s) {
            const bf16x8 af = *(const bf16x8*)&pre_pack[(s * 64 + lane) * 8];
            #pragma unroll
            for (int j = 0; j < 4; ++j) {
                const bf16x8 bf = *(const bf16x8*)(bb + ((j * 4 + wave) * 16) * 256 + s * 32);
                acc[j] = __builtin_amdgcn_mfma_f32_16x16x32_bf16(af, bf, acc[j], 0, 0, 0);
            }
        }
        #pragma unroll
        for (int j = 0; j < 4; ++j) {
            const int col = (j * 4 + wave) * 16 + qr;
            const float bo = b_out[col];
            #pragma unroll
            for (int r = 0; r < 4; ++r)
                out[(qbase + quad * 4 + r) * CDIM + col] = acc[j][r] + bo;
        }
    }
}

extern "C" void kernel_launch(void* const* d_in, const int* in_sizes, int n_in,
                              void* d_out, int out_size, void* d_ws, size_t ws_size,
                              hipStream_t stream) {
    const float* query   = (const float*)d_in[0];
    const float* ref_pts = (const float*)d_in[1];
    const float* feat    = (const float*)d_in[2];
    const float* W_off  = (const float*)d_in[5];
    const float* b_off  = (const float*)d_in[6];
    const float* W_attn = (const float*)d_in[7];
    const float* b_attn = (const float*)d_in[8];
    const float* W_out  = (const float*)d_in[9];
    const float* b_out  = (const float*)d_in[10];
    float* out = (float*)d_out;

    const int B = 2;
    const int Len = in_sizes[1] / (B * 2);
    const int rows = B * Len;                    // 43520
    const size_t feat_elems = (size_t)rows * CDIM;

    // ws layout (bytes)
    const size_t off_wt     = 0;                 // 327680 B (shorts)
    const size_t off_featbf = 327680;            // feat_elems*2
    const size_t off_offs   = off_featbf + feat_elems * 2;           // rows*256*4
    const size_t off_aw     = off_offs + (size_t)rows * 256 * 4;     // rows*128*4
    const size_t off_pre    = off_aw + (size_t)rows * 128 * 4;       // rows*256*2
    const size_t need_full  = off_pre + (size_t)rows * 256 * 2;
    const size_t need_feat  = off_featbf + feat_elems * 2;

    char* ws = (char*)d_ws;
    short* wt = (short*)(ws + off_wt);

    convert_w<<<640, 256, 0, stream>>>(W_off, W_attn, W_out, wt);

    if (ws_size >= need_full) {
        short* featbf = (short*)(ws + off_featbf);
        float* offs_g = (float*)(ws + off_offs);
        float* aw_g   = (float*)(ws + off_aw);
        short* pre_g  = (short*)(ws + off_pre);
        const int n4 = (int)(feat_elems / 4);
        convert_feat<<<(n4 + 255) / 256, 256, 0, stream>>>(feat, featbf, n4);
        gemm1_kernel<<<rows / QB, 256, 0, stream>>>(query, wt, b_off, b_attn, offs_g, aw_g);
        sampler_kernel<<<rows / 8, 256, 0, stream>>>(ref_pts, featbf, offs_g, aw_g, pre_g, Len);
        gemm2_kernel<<<rows / QB, 256, 0, stream>>>(pre_g, wt, b_out, out);
    } else if (ws_size >= need_feat) {
        short* featbf = (short*)(ws + off_featbf);
        const int n4 = (int)(feat_elems / 4);
        convert_feat<<<(n4 + 255) / 256, 256, 0, stream>>>(feat, featbf, n4);
        msda_fused_fb<1><<<rows / QB, 256, 0, stream>>>(query, ref_pts, feat, featbf, wt,
                                                        b_off, b_attn, b_out, out, Len);
    } else {
        msda_fused_fb<0><<<rows / QB, 256, 0, stream>>>(query, ref_pts, feat, (const short*)nullptr,
                                                        wt, b_off, b_attn, b_out, out, Len);
    }
}

// Round 5
// 337.846 us; speedup vs baseline: 3.9946x; 1.2307x over previous
//
#include <hip/hip_runtime.h>

// MSDeformAttn — R5: coalesced gemm1 stores (natural layout, sampler permutes on
// read), fp16 features + packed v_pk_fma_f16 lerp, clamp+mask gathers.
// Pipeline: convert_w / convert_feat_f16 -> gemm1 -> sampler -> gemm2.
// B=2, C=256, nH=8, nL=4, nP=4, hd=32, Len=21760.
// Shapes compile-time: [[128,128],[64,64],[32,32],[16,16]], starts [0,16384,20480,21504].

#define NH 8
#define NL 4
#define NP 4
#define CDIM 256
#define HD 32
#define QB 16

typedef short bf16x8 __attribute__((ext_vector_type(8)));
typedef float f32x4  __attribute__((ext_vector_type(4)));
typedef _Float16 f16x8v __attribute__((ext_vector_type(8)));
typedef _Float16 f16x4v __attribute__((ext_vector_type(4)));

#define SPLAT8(x) (f16x8v){(x),(x),(x),(x),(x),(x),(x),(x)}

__device__ __forceinline__ short f2bf(float x) {
    union { float f; unsigned u; } v; v.f = x;
    const unsigned r = v.u + 0x7FFFu + ((v.u >> 16) & 1u);
    return (short)(r >> 16);
}
__device__ __forceinline__ float bf2f(short s) {
    union { unsigned u; float f; } v; v.u = ((unsigned)(unsigned short)s) << 16;
    return v.f;
}

__constant__ int LVL_S_C[4] = {0, 16384, 20480, 21504};

// ---- converts ----
__global__ __launch_bounds__(256) void convert_w(
    const float* __restrict__ W_off, const float* __restrict__ W_attn,
    const float* __restrict__ W_out, short* __restrict__ wt)
{
    const int gid = blockIdx.x * 256 + threadIdx.x;
    if (gid < 65536) {
        const int c = gid >> 8, k = gid & 255;
        wt[gid] = f2bf(W_off[k * 256 + c]);
    } else if (gid < 98304) {
        const int g = gid - 65536, c = g >> 8, k = g & 255;
        wt[gid] = f2bf(W_attn[k * 128 + c]);
    } else if (gid < 163840) {
        const int g = gid - 98304, c = g >> 8, k = g & 255;
        wt[gid] = f2bf(W_out[k * 256 + c]);
    }
}

__global__ __launch_bounds__(256) void convert_feat_f16(
    const float* __restrict__ feat, _Float16* __restrict__ fh, int n4)
{
    const int gid = blockIdx.x * 256 + threadIdx.x;
    if (gid < n4) {
        const float4 v = *(const float4*)&feat[gid * 4];
        f16x4v o;
        o[0] = (_Float16)v.x; o[1] = (_Float16)v.y;
        o[2] = (_Float16)v.z; o[3] = (_Float16)v.w;
        *(f16x4v*)&fh[gid * 4] = o;
    }
}

// ---- gemm1: offs (N=256) + attn logits (N=128), 16 rows/block, coalesced stores ----
__global__ __launch_bounds__(256) void gemm1_kernel(
    const float* __restrict__ query, const short* __restrict__ wt,
    const float* __restrict__ b_off, const float* __restrict__ b_attn,
    float* __restrict__ offs_g, float* __restrict__ aw_g)
{
    const int t = threadIdx.x;
    const int lane = t & 63;
    const int wave = t >> 6;
    const int qr = lane & 15;
    const int quad = lane >> 4;
    const long long qbase = (long long)blockIdx.x * QB;

    __shared__ __align__(16) short qp[QB * CDIM];  // packed A-frags, lane-linear

    #pragma unroll
    for (int it = 0; it < 4; ++it) {
        const int e = it * 1024 + t * 4;
        const int i = e >> 8, k = e & 255;
        const float4 v = *(const float4*)&query[(qbase + i) * CDIM + k];
        const int chunk = (k >> 5) * 64 + ((k >> 3) & 3) * 16 + i;
        short4 o;
        o.x = f2bf(v.x); o.y = f2bf(v.y); o.z = f2bf(v.z); o.w = f2bf(v.w);
        *(short4*)&qp[chunk * 8 + (k & 7)] = o;
    }
    __syncthreads();

    const short* __restrict__ Wt_off  = wt;
    const short* __restrict__ Wt_attn = wt + 65536;

    f32x4 acc[4], acca[2];
    #pragma unroll
    for (int j = 0; j < 4; ++j) acc[j] = (f32x4){0.f, 0.f, 0.f, 0.f};
    #pragma unroll
    for (int j = 0; j < 2; ++j) acca[j] = (f32x4){0.f, 0.f, 0.f, 0.f};

    const short* bb_off  = Wt_off  + qr * 256 + quad * 8;
    const short* bb_attn = Wt_attn + qr * 256 + quad * 8;
    #pragma unroll
    for (int s = 0; s < 8; ++s) {
        const bf16x8 af = *(const bf16x8*)&qp[(s * 64 + lane) * 8];
        #pragma unroll
        for (int j = 0; j < 4; ++j) {
            const bf16x8 bf = *(const bf16x8*)(bb_off + ((j * 4 + wave) * 16) * 256 + s * 32);
            acc[j] = __builtin_amdgcn_mfma_f32_16x16x32_bf16(af, bf, acc[j], 0, 0, 0);
        }
        #pragma unroll
        for (int j = 0; j < 2; ++j) {
            const bf16x8 bf = *(const bf16x8*)(bb_attn + ((j * 4 + wave) * 16) * 256 + s * 32);
            acca[j] = __builtin_amdgcn_mfma_f32_16x16x32_bf16(af, bf, acca[j], 0, 0, 0);
        }
    }
    // D layout: col = qr, row = quad*4 + r. Natural-layout coalesced stores:
    // lanes of a quad write 16 consecutive floats (64B segments).
    #pragma unroll
    for (int j = 0; j < 4; ++j) {
        const int col = (j * 4 + wave) * 16 + qr;
        const float bo = b_off[col];
        #pragma unroll
        for (int r = 0; r < 4; ++r)
            offs_g[(qbase + quad * 4 + r) * 256 + col] = acc[j][r] + bo;
    }
    #pragma unroll
    for (int j = 0; j < 2; ++j) {
        const int col = (j * 4 + wave) * 16 + qr;
        const float ba = b_attn[col];
        #pragma unroll
        for (int r = 0; r < 4; ++r)
            aw_g[(qbase + quad * 4 + r) * 128 + col] = acca[j][r] + ba;
    }
}

// ---- sampler: 8 rows/block, 32 lanes/row (h = l32>>2, ct = l32&3, 8 fp16 ch) ----
__global__ __launch_bounds__(256) void sampler_kernel(
    const float* __restrict__ ref_pts, const _Float16* __restrict__ featfh,
    const float* __restrict__ offs_g, const float* __restrict__ aw_g,
    short* __restrict__ pre_g, int Len)
{
    const int t = threadIdx.x;
    const int rl = t >> 5;
    const int l32 = t & 31;
    const int h = l32 >> 2, ct = l32 & 3;
    const int row = blockIdx.x * 8 + rl;
    const int b = row / Len;

    const float rx = ref_pts[row * 2];
    const float ry = ref_pts[row * 2 + 1];
    const float* __restrict__ offr = offs_g + (long long)row * 256 + h * 32;  // [pi*2+xy]
    const float* __restrict__ awr  = aw_g  + (long long)row * 128 + h * 16;   // [pi]

    // softmax stats (streamed; exp recomputed per point to stay register-lean)
    float mxv = -1e30f;
    #pragma unroll
    for (int j = 0; j < 16; ++j) mxv = fmaxf(mxv, awr[j]);
    float ssum = 0.f;
    #pragma unroll
    for (int j = 0; j < 16; ++j) ssum += __expf(awr[j] - mxv);
    const float inv = 1.f / ssum;

    const int c0 = h * HD + ct * 8;
    float acc[8];
    #pragma unroll
    for (int c = 0; c < 8; ++c) acc[c] = 0.f;

    #pragma unroll
    for (int l = 0; l < NL; ++l) {
        const int Wl = 128 >> l;
        const int base = (b * Len + LVL_S_C[l]) * CDIM + c0;
        #pragma unroll
        for (int p = 0; p < NP; ++p) {
            const int pi = l * 4 + p;
            const float ox = offr[pi * 2];
            const float oy = offr[pi * 2 + 1];
            const float a  = __expf(awr[pi] - mxv) * inv;
            const float x = fmaf(rx, (float)Wl, ox) - 0.5f;
            const float y = fmaf(ry, (float)Wl, oy) - 0.5f;
            const float xf = floorf(x), yf = floorf(y);
            const int x0 = (int)xf, y0 = (int)yf;
            const float wx = x - xf, wy = y - yf;
            // validity folded into weights; loads unconditional at clamped addrs
            const float ax0 = ((unsigned)x0     < (unsigned)Wl) ? (1.f - wx) : 0.f;
            const float ax1 = ((unsigned)(x0+1) < (unsigned)Wl) ? wx         : 0.f;
            const float ay0 = (((unsigned)y0     < (unsigned)Wl) ? (1.f - wy) : 0.f) * a;
            const float ay1 = (((unsigned)(y0+1) < (unsigned)Wl) ? wy         : 0.f) * a;
            const int x0c = min(max(x0, 0), Wl - 1), x1c = min(max(x0 + 1, 0), Wl - 1);
            const int y0c = min(max(y0, 0), Wl - 1), y1c = min(max(y0 + 1, 0), Wl - 1);
            const int r00 = base + (y0c * Wl + x0c) * CDIM;
            const int r01 = base + (y0c * Wl + x1c) * CDIM;
            const int r10 = base + (y1c * Wl + x0c) * CDIM;
            const int r11 = base + (y1c * Wl + x1c) * CDIM;
            const f16x8v v00 = *(const f16x8v*)(featfh + r00);
            const f16x8v v01 = *(const f16x8v*)(featfh + r01);
            const f16x8v v10 = *(const f16x8v*)(featfh + r10);
            const f16x8v v11 = *(const f16x8v*)(featfh + r11);
            const f16x8v W00 = SPLAT8((_Float16)(ax0 * ay0));
            const f16x8v W01 = SPLAT8((_Float16)(ax1 * ay0));
            const f16x8v W10 = SPLAT8((_Float16)(ax0 * ay1));
            const f16x8v W11 = SPLAT8((_Float16)(ax1 * ay1));
            const f16x8v bil = v00 * W00 + v01 * W01 + v10 * W10 + v11 * W11;
            #pragma unroll
            for (int c = 0; c < 8; ++c) acc[c] += (float)bil[c];
        }
    }
    bf16x8 pv;
    #pragma unroll
    for (int c = 0; c < 8; ++c) pv[c] = f2bf(acc[c]);
    // packed A-frag layout for gemm2: tile = row>>4, chunk = h*64 + ct*16 + (row&15)
    *(bf16x8*)&pre_g[(long long)(row >> 4) * 4096 + (h * 64 + ct * 16 + (row & 15)) * 8] = pv;
}

// ---- gemm2: out = pre @ W_out + b_out, 16 rows/block, no LDS ----
__global__ __launch_bounds__(256) void gemm2_kernel(
    const short* __restrict__ pre_g, const short* __restrict__ wt,
    const float* __restrict__ b_out, float* __restrict__ out)
{
    const int t = threadIdx.x;
    const int lane = t & 63;
    const int wave = t >> 6;
    const int qr = lane & 15;
    const int quad = lane >> 4;
    const long long qbase = (long long)blockIdx.x * QB;
    const short* __restrict__ ap = pre_g + (long long)blockIdx.x * 4096;
    const short* __restrict__ Wt_out = wt + 98304;

    f32x4 acc[4];
    #pragma unroll
    for (int j = 0; j < 4; ++j) acc[j] = (f32x4){0.f, 0.f, 0.f, 0.f};
    const short* bb = Wt_out + qr * 256 + quad * 8;
    #pragma unroll
    for (int s = 0; s < 8; ++s) {
        const bf16x8 af = *(const bf16x8*)&ap[(s * 64 + lane) * 8];
        #pragma unroll
        for (int j = 0; j < 4; ++j) {
            const bf16x8 bf = *(const bf16x8*)(bb + ((j * 4 + wave) * 16) * 256 + s * 32);
            acc[j] = __builtin_amdgcn_mfma_f32_16x16x32_bf16(af, bf, acc[j], 0, 0, 0);
        }
    }
    #pragma unroll
    for (int j = 0; j < 4; ++j) {
        const int col = (j * 4 + wave) * 16 + qr;
        const float bo = b_out[col];
        #pragma unroll
        for (int r = 0; r < 4; ++r)
            out[(qbase + quad * 4 + r) * CDIM + col] = acc[j][r] + bo;
    }
}

// ---- fallback: fused kernel, fp32 features, used only if ws too small ----
__global__ __launch_bounds__(256) void msda_fused_fb(
    const float* __restrict__ query, const float* __restrict__ ref_pts,
    const float* __restrict__ feat_f32, const short* __restrict__ wt,
    const float* __restrict__ b_off, const float* __restrict__ b_attn,
    const float* __restrict__ b_out, float* __restrict__ out, int Len)
{
    const int t = threadIdx.x;
    const int lane = t & 63;
    const int wave = t >> 6;
    const int qr = lane & 15;
    const int quad = lane >> 4;
    const long long qbase = (long long)blockIdx.x * QB;
    const int b = (int)(qbase / Len);

    __shared__ __align__(16) char uni[QB * CDIM * 4];
    short* qp = (short*)uni;
    float* offs_sm = (float*)uni;
    __shared__ float aw_sm[QB][NH * NL * NP + 4];
    __shared__ __align__(16) short pre_pack[QB * CDIM];
    __shared__ float ref_sm[QB][2];

    #pragma unroll
    for (int it = 0; it < 4; ++it) {
        const int e = it * 1024 + t * 4;
        const int i = e >> 8, k = e & 255;
        const float4 v = *(const float4*)&query[(qbase + i) * CDIM + k];
        const int chunk = (k >> 5) * 64 + ((k >> 3) & 3) * 16 + i;
        short4 o;
        o.x = f2bf(v.x); o.y = f2bf(v.y); o.z = f2bf(v.z); o.w = f2bf(v.w);
        *(short4*)&qp[chunk * 8 + (k & 7)] = o;
    }
    if (t < QB * 2) ref_sm[t >> 1][t & 1] = ref_pts[(qbase + (t >> 1)) * 2 + (t & 1)];
    __syncthreads();

    const short* __restrict__ Wt_off  = wt;
    const short* __restrict__ Wt_attn = wt + 65536;
    const short* __restrict__ Wt_out  = wt + 98304;

    {
        f32x4 acc[4], acca[2];
        #pragma unroll
        for (int j = 0; j < 4; ++j) acc[j] = (f32x4){0.f, 0.f, 0.f, 0.f};
        #pragma unroll
        for (int j = 0; j < 2; ++j) acca[j] = (f32x4){0.f, 0.f, 0.f, 0.f};
        const short* bb_off  = Wt_off  + qr * 256 + quad * 8;
        const short* bb_attn = Wt_attn + qr * 256 + quad * 8;
        #pragma unroll
        for (int s = 0; s < 8; ++s) {
            const bf16x8 af = *(const bf16x8*)&qp[(s * 64 + lane) * 8];
            #pragma unroll
            for (int j = 0; j < 4; ++j) {
                const bf16x8 bf = *(const bf16x8*)(bb_off + ((j * 4 + wave) * 16) * 256 + s * 32);
                acc[j] = __builtin_amdgcn_mfma_f32_16x16x32_bf16(af, bf, acc[j], 0, 0, 0);
            }
            #pragma unroll
            for (int j = 0; j < 2; ++j) {
                const bf16x8 bf = *(const bf16x8*)(bb_attn + ((j * 4 + wave) * 16) * 256 + s * 32);
                acca[j] = __builtin_amdgcn_mfma_f32_16x16x32_bf16(af, bf, acca[j], 0, 0, 0);
            }
        }
        __syncthreads();
        #pragma unroll
        for (int j = 0; j < 4; ++j) {
            const int col = (j * 4 + wave) * 16 + qr;
            const float bo = b_off[col];
            const int hh = col >> 5, rem = col & 31;
            #pragma unroll
            for (int r = 0; r < 4; ++r)
                offs_sm[(quad * 4 + r) * 256 + rem * 8 + hh] = acc[j][r] + bo;
        }
        #pragma unroll
        for (int j = 0; j < 2; ++j) {
            const int col = (j * 4 + wave) * 16 + qr;
            const float ba = b_attn[col];
            const int hh = col >> 4, rem = col & 15;
            #pragma unroll
            for (int r = 0; r < 4; ++r)
                aw_sm[quad * 4 + r][rem * 8 + hh] = acca[j][r] + ba;
        }
    }
    __syncthreads();

    if (t < QB * NH) {
        const int i = t >> 3, hh = t & 7;
        float vals[16], mx = -1e30f;
        #pragma unroll
        for (int j = 0; j < 16; ++j) { vals[j] = aw_sm[i][j * 8 + hh]; mx = fmaxf(mx, vals[j]); }
        float s = 0.f;
        #pragma unroll
        for (int j = 0; j < 16; ++j) { vals[j] = __expf(vals[j] - mx); s += vals[j]; }
        const float inv = 1.f / s;
        #pragma unroll
        for (int j = 0; j < 16; ++j) aw_sm[i][j * 8 + hh] = vals[j] * inv;
    }
    __syncthreads();

    {
        const int q2 = lane >> 5;
        const int hh = (lane >> 2) & 7;
        const int ct = lane & 3;
        const int c0 = hh * HD + ct * 8;
        #pragma unroll 1
        for (int it = 0; it < 2; ++it) {
            const int i = wave * 4 + it * 2 + q2;
            const float rx = ref_sm[i][0], ry = ref_sm[i][1];
            float acc[8];
            #pragma unroll
            for (int c = 0; c < 8; ++c) acc[c] = 0.f;
            #pragma unroll
            for (int l = 0; l < NL; ++l) {
                const int Wl = 128 >> l;
                const int base = (b * Len + LVL_S_C[l]) * CDIM + c0;
                #pragma unroll 2
                for (int p = 0; p < NP; ++p) {
                    const int pi = l * 4 + p;
                    const float ox = offs_sm[i * 256 + (pi * 2) * 8 + hh];
                    const float oy = offs_sm[i * 256 + (pi * 2 + 1) * 8 + hh];
                    const float a  = aw_sm[i][pi * 8 + hh];
                    const float x = fmaf(rx, (float)Wl, ox) - 0.5f;
                    const float y = fmaf(ry, (float)Wl, oy) - 0.5f;
                    const float xf = floorf(x), yf = floorf(y);
                    const int x0 = (int)xf, y0 = (int)yf;
                    const float wx = x - xf, wy = y - yf;
                    const float ax0 = ((unsigned)x0     < (unsigned)Wl) ? (1.f - wx) : 0.f;
                    const float ax1 = ((unsigned)(x0+1) < (unsigned)Wl) ? wx         : 0.f;
                    const float ay0 = (((unsigned)y0     < (unsigned)Wl) ? (1.f - wy) : 0.f) * a;
                    const float ay1 = (((unsigned)(y0+1) < (unsigned)Wl) ? wy         : 0.f) * a;
                    const int x0c = min(max(x0, 0), Wl - 1), x1c = min(max(x0 + 1, 0), Wl - 1);
                    const int y0c = min(max(y0, 0), Wl - 1), y1c = min(max(y0 + 1, 0), Wl - 1);
                    const float w00 = ax0 * ay0, w01 = ax1 * ay0;
                    const float w10 = ax0 * ay1, w11 = ax1 * ay1;
                    const int r0 = base + (y0c * Wl + x0c) * CDIM;
                    const int r1 = base + (y0c * Wl + x1c) * CDIM;
                    const int r2 = base + (y1c * Wl + x0c) * CDIM;
                    const int r3 = base + (y1c * Wl + x1c) * CDIM;
                    f32x4 a0 = *(const f32x4*)(feat_f32 + r0);
                    f32x4 a1 = *(const f32x4*)(feat_f32 + r0 + 4);
                    f32x4 b0 = *(const f32x4*)(feat_f32 + r1);
                    f32x4 b1 = *(const f32x4*)(feat_f32 + r1 + 4);
                    f32x4 c0v = *(const f32x4*)(feat_f32 + r2);
                    f32x4 c1 = *(const f32x4*)(feat_f32 + r2 + 4);
                    f32x4 d0 = *(const f32x4*)(feat_f32 + r3);
                    f32x4 d1 = *(const f32x4*)(feat_f32 + r3 + 4);
                    #pragma unroll
                    for (int c = 0; c < 4; ++c) {
                        acc[c]     += w00*a0[c] + w01*b0[c] + w10*c0v[c] + w11*d0[c];
                        acc[c + 4] += w00*a1[c] + w01*b1[c] + w10*c1[c]  + w11*d1[c];
                    }
                }
            }
            bf16x8 pv;
            #pragma unroll
            for (int c = 0; c < 8; ++c) pv[c] = f2bf(acc[c]);
            *(bf16x8*)&pre_pack[(hh * 64 + ct * 16 + i) * 8] = pv;
        }
    }
    __syncthreads();

    {
        f32x4 acc[4];
        #pragma unroll
        for (int j = 0; j < 4; ++j) acc[j] = (f32x4){0.f, 0.f, 0.f, 0.f};
        const short* bb = Wt_out + qr * 256 + quad * 8;
        #pragma unroll
        for (int s = 0; s < 8; ++s) {
            const bf16x8 af = *(const bf16x8*)&pre_pack[(s * 64 + lane) * 8];
            #pragma unroll
            for (int j = 0; j < 4; ++j) {
                const bf16x8 bf = *(const bf16x8*)(bb + ((j * 4 + wave) * 16) * 256 + s * 32);
                acc[j] = __builtin_amdgcn_mfma_f32_16x16x32_bf16(af, bf, acc[j], 0, 0, 0);
            }
        }
        #pragma unroll
        for (int j = 0; j < 4; ++j) {
            const int col = (j * 4 + wave) * 16 + qr;
            const float bo = b_out[col];
            #pragma unroll
            for (int r = 0; r < 4; ++r)
                out[(qbase + quad * 4 + r) * CDIM + col] = acc[j][r] + bo;
        }
    }
}

extern "C" void kernel_launch(void* const* d_in, const int* in_sizes, int n_in,
                              void* d_out, int out_size, void* d_ws, size_t ws_size,
                              hipStream_t stream) {
    const float* query   = (const float*)d_in[0];
    const float* ref_pts = (const float*)d_in[1];
    const float* feat    = (const float*)d_in[2];
    const float* W_off  = (const float*)d_in[5];
    const float* b_off  = (const float*)d_in[6];
    const float* W_attn = (const float*)d_in[7];
    const float* b_attn = (const float*)d_in[8];
    const float* W_out  = (const float*)d_in[9];
    const float* b_out  = (const float*)d_in[10];
    float* out = (float*)d_out;

    const int B = 2;
    const int Len = in_sizes[1] / (B * 2);
    const int rows = B * Len;                    // 43520
    const size_t feat_elems = (size_t)rows * CDIM;

    // ws layout (bytes)
    const size_t off_wt     = 0;                 // 327680
    const size_t off_feath  = 327680;            // feat_elems*2 (fp16)
    const size_t off_offs   = off_feath + feat_elems * 2;            // rows*256*4
    const size_t off_aw     = off_offs + (size_t)rows * 256 * 4;     // rows*128*4
    const size_t off_pre    = off_aw + (size_t)rows * 128 * 4;       // rows*256*2
    const size_t need_full  = off_pre + (size_t)rows * 256 * 2;

    char* ws = (char*)d_ws;
    short* wt = (short*)(ws + off_wt);

    convert_w<<<640, 256, 0, stream>>>(W_off, W_attn, W_out, wt);

    if (ws_size >= need_full) {
        _Float16* feath = (_Float16*)(ws + off_feath);
        float* offs_g = (float*)(ws + off_offs);
        float* aw_g   = (float*)(ws + off_aw);
        short* pre_g  = (short*)(ws + off_pre);
        const int n4 = (int)(feat_elems / 4);
        convert_feat_f16<<<(n4 + 255) / 256, 256, 0, stream>>>(feat, feath, n4);
        gemm1_kernel<<<rows / QB, 256, 0, stream>>>(query, wt, b_off, b_attn, offs_g, aw_g);
        sampler_kernel<<<rows / 8, 256, 0, stream>>>(ref_pts, feath, offs_g, aw_g, pre_g, Len);
        gemm2_kernel<<<rows / QB, 256, 0, stream>>>(pre_g, wt, b_out, out);
    } else {
        msda_fused_fb<<<rows / QB, 256, 0, stream>>>(query, ref_pts, feat, wt,
                                                     b_off, b_attn, b_out, out, Len);
    }
}